// Round 4
// baseline (1802.067 us; speedup 1.0000x reference)
//
#include <hip/hip_runtime.h>

#define N_TOK 32768
#define DIM   256
#define KCB   4096
#define MROWS 32           // rows per block (main kernel)
#define KT    256          // k-tile per outer iter
#define NKT   (KCB / KT)   // 16
#define DC    16           // d-chunk staged in LDS
#define NDC   (DIM / DC)   // 16
#define ESD   20           // es row stride (16 + 4 pad)
#define XSD   260          // xs row stride (256 + 4 pad)

// ws layout (bytes):
//   0   : double lossAcc   (zeroed by 16B memset)
//   16  : float A[N_TOK]   -- numpy-replica fp32 ||x_i||^2   (131072 B)
//   131088: float C[KCB]   -- fp32 ||e_k||^2 (fp64 sum, rounded once)
#define WS_A 16
#define WS_C (16 + 4 * N_TOK)

// ---------------------------------------------------------------------------
// Kernel A: bit-exact replica of numpy's fp32 pairwise row sum-of-squares,
// npyv/AVX-512 order: n=256 -> split 128+128; each 128-block = 8 zmm lanesums
// p[l] = ((t[l]+t[16+l])+(t[32+l]+t[48+l]))+((t[64+l]+t[80+l])+(t[96+l]+t[112+l])),
// then stride-halving horizontal tree (8,4,2,1); A = B(first128) + B(second128).
__global__ __launch_bounds__(256) void xsq_np_kernel(const float* __restrict__ x,
                                                     float* __restrict__ A) {
#pragma clang fp contract(off)
    __shared__ float xr[4][256];
    const int tid = threadIdx.x;
    const int w = tid >> 6, l = tid & 63;
    const int row = blockIdx.x * 4 + w;
    float4 v = *(const float4*)(x + (size_t)row * DIM + l * 4);
    xr[w][l * 4 + 0] = v.x; xr[w][l * 4 + 1] = v.y;
    xr[w][l * 4 + 2] = v.z; xr[w][l * 4 + 3] = v.w;
    __syncthreads();
    const float* t = xr[w];
    const int g = (l >> 4) & 1;          // half: lanes 0..15 -> first 128, 16..31 -> second
    const int j = l & 15;
    const int base = g * 128 + j;
    float t0 = t[base +   0] * t[base +   0];
    float t1 = t[base +  16] * t[base +  16];
    float t2 = t[base +  32] * t[base +  32];
    float t3 = t[base +  48] * t[base +  48];
    float t4 = t[base +  64] * t[base +  64];
    float t5 = t[base +  80] * t[base +  80];
    float t6 = t[base +  96] * t[base +  96];
    float t7 = t[base + 112] * t[base + 112];
    float p = ((t0 + t1) + (t2 + t3)) + ((t4 + t5) + (t6 + t7));
    p = p + __shfl_xor(p, 8, 64);        // horizontal tree: l<->l+8
    p = p + __shfl_xor(p, 4, 64);        // l<->l+4
    p = p + __shfl_xor(p, 2, 64);        // l<->l+2
    p = p + __shfl_xor(p, 1, 64);        // l<->l+1  (lane0/lane16 hold block sums)
    float other = __shfl(p, 16, 64);     // second-half block sum
    if (l == 0) A[row] = p + other;      // top-level pairwise combine
}

// ---------------------------------------------------------------------------
// Kernel B: C[k] = fl32( fp64 sum of fl32(e_d^2) ). Matches numpy's fp32
// pairwise sum to ~1e-12 (boundary-flip probability negligible at 5e-6 scale).
__global__ void esq_np_kernel(const float* __restrict__ emb, float* __restrict__ C) {
#pragma clang fp contract(off)
    int row  = blockIdx.x * 4 + (threadIdx.x >> 6);
    int lane = threadIdx.x & 63;
    float4 v = *(const float4*)(emb + (size_t)row * DIM + lane * 4);
    float s0 = v.x * v.x, s1 = v.y * v.y, s2 = v.z * v.z, s3 = v.w * v.w;
    double q = (double)s0 + (double)s1 + (double)s2 + (double)s3;
    #pragma unroll
    for (int off = 32; off; off >>= 1) q += __shfl_xor(q, off, 64);
    if (lane == 0) C[row] = (float)q;
}

// ---------------------------------------------------------------------------
// Kernel C: fp32 np-replica argmin. Score s = fl32(fl32(A - 2*dot) + C),
// first-occurrence (lowest k) min, matching np.argmin semantics.
__global__ __launch_bounds__(256, 2) void vq_np(
    const float* __restrict__ x,      // [N_TOK, DIM]
    const float* __restrict__ emb,    // [KCB, DIM]
    const float* __restrict__ A,      // [N_TOK] fp32 ||x||^2 (numpy order)
    const float* __restrict__ C,      // [KCB]  fp32 ||e||^2
    float* __restrict__ out,          // [1 + N*D + N]
    double* __restrict__ lossAcc)
{
    __shared__ float xs[MROWS][XSD];
    __shared__ float es[KT][ESD];
    __shared__ float sA[MROWS];
    __shared__ int   sIdx[MROWS];
    __shared__ double sRed[4];

    const int tid = threadIdx.x;
    const int c = tid & 31;        // k-column group (32)
    const int r = tid >> 5;        // row group (8), each owns 4 rows
    const int rowBase = blockIdx.x * MROWS;

    if (tid < MROWS) sA[tid] = A[rowBase + tid];

    // ---- stage x tile once: 32 rows x 256 d ----
    #pragma unroll
    for (int p = 0; p < 8; ++p) {
        int row = (tid >> 6) + 4 * p;
        int d   = (tid & 63) * 4;
        float4 v = *(const float4*)(x + (size_t)(rowBase + row) * DIM + d);
        *(float4*)&xs[row][d] = v;
    }

    float m1[4];
    int   i1[4];
    #pragma unroll
    for (int ri = 0; ri < 4; ++ri) { m1[ri] = 3.4e38f; i1[ri] = 0; }

    __syncthreads();

    // ---- main loop over k-tiles ----
    for (int kt = 0; kt < NKT; ++kt) {
        float acc[4][8];
        #pragma unroll
        for (int ri = 0; ri < 4; ++ri)
            #pragma unroll
            for (int kk = 0; kk < 8; ++kk) acc[ri][kk] = 0.f;

        for (int dc = 0; dc < NDC; ++dc) {
            #pragma unroll
            for (int p = 0; p < 4; ++p) {
                int kloc = (tid >> 2) + 64 * p;
                int dl   = (tid & 3) * 4;
                float4 v = *(const float4*)(emb + (size_t)(kt * KT + kloc) * DIM + dc * DC + dl);
                *(float4*)&es[kloc][dl] = v;
            }
            __syncthreads();
            #pragma unroll
            for (int d4 = 0; d4 < 4; ++d4) {
                float4 xf[4], ef[8];
                #pragma unroll
                for (int ri = 0; ri < 4; ++ri)
                    xf[ri] = *(const float4*)&xs[r * 4 + ri][dc * DC + d4 * 4];
                #pragma unroll
                for (int kk = 0; kk < 8; ++kk)
                    ef[kk] = *(const float4*)&es[c + 32 * kk][d4 * 4];
                #pragma unroll
                for (int ri = 0; ri < 4; ++ri)
                    #pragma unroll
                    for (int kk = 0; kk < 8; ++kk) {
                        acc[ri][kk] = fmaf(xf[ri].x, ef[kk].x, acc[ri][kk]);
                        acc[ri][kk] = fmaf(xf[ri].y, ef[kk].y, acc[ri][kk]);
                        acc[ri][kk] = fmaf(xf[ri].z, ef[kk].z, acc[ri][kk]);
                        acc[ri][kk] = fmaf(xf[ri].w, ef[kk].w, acc[ri][kk]);
                    }
            }
            __syncthreads();
        }
        // scores with np fp32 rounding semantics; k ascending -> strict < keeps first
        #pragma unroll
        for (int kk = 0; kk < 8; ++kk) {
            int kg = kt * KT + c + 32 * kk;
            float Ck = C[kg];
            #pragma unroll
            for (int ri = 0; ri < 4; ++ri) {
                float tmp = sA[r * 4 + ri] - 2.0f * acc[ri][kk];  // == fl32(A - 2*dot)
                float s   = tmp + Ck;                              // fl32(tmp + C)
                if (s < m1[ri]) { m1[ri] = s; i1[ri] = kg; }
            }
        }
    }

    // ---- cross-lane argmin merge (lexicographic: value, then lowest index) ----
    #pragma unroll
    for (int ri = 0; ri < 4; ++ri) {
        float a = m1[ri]; int ja = i1[ri];
        #pragma unroll
        for (int off = 1; off <= 16; off <<= 1) {
            float b  = __shfl_xor(a, off, 64);
            int   jb = __shfl_xor(ja, off, 64);
            if (b < a || (b == a && jb < ja)) { a = b; ja = jb; }
        }
        if (c == 0) sIdx[r * 4 + ri] = ja;
    }
    __syncthreads();

    // ---- outputs: index (as float), quantized (exact gather), loss partial ----
    if (tid < MROWS) {
        out[1 + (size_t)N_TOK * DIM + rowBase + tid] = (float)sIdx[tid];
    }
    double lsum = 0.0;
    for (int row = 0; row < MROWS; ++row) {
        int idx = sIdx[row];
        float q  = emb[(size_t)idx * DIM + tid];
        float xv = xs[row][tid];
        out[1 + (size_t)(rowBase + row) * DIM + tid] = q;
        double df = (double)q - (double)xv;
        lsum += df * df;
    }
    #pragma unroll
    for (int off = 1; off < 64; off <<= 1) lsum += __shfl_xor(lsum, off, 64);
    __syncthreads();
    if ((tid & 63) == 0) sRed[tid >> 6] = lsum;
    __syncthreads();
    if (tid == 0) {
        atomicAdd(lossAcc, sRed[0] + sRed[1] + sRed[2] + sRed[3]);
    }
}

// ---------------------------------------------------------------------------
__global__ void finalize_kernel(const double* __restrict__ lossAcc, float* __restrict__ out) {
    out[0] = (float)(0.5 * (*lossAcc) / (double)((size_t)N_TOK * DIM));
}

extern "C" void kernel_launch(void* const* d_in, const int* in_sizes, int n_in,
                              void* d_out, int out_size, void* d_ws, size_t ws_size,
                              hipStream_t stream) {
    const float* x   = (const float*)d_in[0];   // [16,2048,256] fp32
    const float* emb = (const float*)d_in[1];   // [4096,256] fp32
    float* out = (float*)d_out;

    double* lossAcc = (double*)d_ws;
    float*  A       = (float*)((char*)d_ws + WS_A);
    float*  C       = (float*)((char*)d_ws + WS_C);

    hipMemsetAsync(d_ws, 0, 16, stream);
    xsq_np_kernel<<<N_TOK / 4, 256, 0, stream>>>(x, A);
    esq_np_kernel<<<KCB / 4, 256, 0, stream>>>(emb, C);
    vq_np<<<N_TOK / MROWS, 256, 0, stream>>>(x, emb, A, C, out, lossAcc);
    finalize_kernel<<<1, 1, 0, stream>>>(lossAcc, out);
}

// Round 5
// 987.828 us; speedup vs baseline: 1.8243x; 1.8243x over previous
//
#include <hip/hip_runtime.h>

#define N_TOK 32768
#define DIM   256
#define KCB   4096
#define MROWS 64           // rows per block; 8 per thread
#define KT    256          // k-tile per outer iter
#define NKT   (KCB / KT)   // 16
#define DC    8            // d-chunk staged in LDS (transposed)
#define NDC   (DIM / DC)   // 32
#define ESD   258          // est row stride (dwords): banks 2(c+d) -> conflict-free float2 reads

// ws layout (bytes):
//   0      : double lossAcc (zeroed by 16B memset)
//   16     : float A[N_TOK] -- numpy-replica fp32 ||x_i||^2
//   131088 : float C[KCB]   -- fp32 ||e_k||^2 (fp64 sum, rounded once)
#define WS_A 16
#define WS_C (16 + 4 * N_TOK)

// ---------------------------------------------------------------------------
// Kernel A: bit-exact replica of numpy's fp32 pairwise row sum-of-squares
// (npyv/AVX-512 order). UNCHANGED from the passing round.
__global__ __launch_bounds__(256) void xsq_np_kernel(const float* __restrict__ x,
                                                     float* __restrict__ A) {
#pragma clang fp contract(off)
    __shared__ float xr[4][256];
    const int tid = threadIdx.x;
    const int w = tid >> 6, l = tid & 63;
    const int row = blockIdx.x * 4 + w;
    float4 v = *(const float4*)(x + (size_t)row * DIM + l * 4);
    xr[w][l * 4 + 0] = v.x; xr[w][l * 4 + 1] = v.y;
    xr[w][l * 4 + 2] = v.z; xr[w][l * 4 + 3] = v.w;
    __syncthreads();
    const float* t = xr[w];
    const int g = (l >> 4) & 1;
    const int j = l & 15;
    const int base = g * 128 + j;
    float t0 = t[base +   0] * t[base +   0];
    float t1 = t[base +  16] * t[base +  16];
    float t2 = t[base +  32] * t[base +  32];
    float t3 = t[base +  48] * t[base +  48];
    float t4 = t[base +  64] * t[base +  64];
    float t5 = t[base +  80] * t[base +  80];
    float t6 = t[base +  96] * t[base +  96];
    float t7 = t[base + 112] * t[base + 112];
    float p = ((t0 + t1) + (t2 + t3)) + ((t4 + t5) + (t6 + t7));
    p = p + __shfl_xor(p, 8, 64);
    p = p + __shfl_xor(p, 4, 64);
    p = p + __shfl_xor(p, 2, 64);
    p = p + __shfl_xor(p, 1, 64);
    float other = __shfl(p, 16, 64);
    if (l == 0) A[row] = p + other;
}

// ---------------------------------------------------------------------------
// Kernel B: C[k] = fl32( fp64 sum of fl32(e_d^2) ). UNCHANGED.
__global__ void esq_np_kernel(const float* __restrict__ emb, float* __restrict__ C) {
#pragma clang fp contract(off)
    int row  = blockIdx.x * 4 + (threadIdx.x >> 6);
    int lane = threadIdx.x & 63;
    float4 v = *(const float4*)(emb + (size_t)row * DIM + lane * 4);
    float s0 = v.x * v.x, s1 = v.y * v.y, s2 = v.z * v.z, s3 = v.w * v.w;
    double q = (double)s0 + (double)s1 + (double)s2 + (double)s3;
    #pragma unroll
    for (int off = 32; off; off >>= 1) q += __shfl_xor(q, off, 64);
    if (lane == 0) C[row] = (float)q;
}

// ---------------------------------------------------------------------------
// Kernel C: fp32 np-replica argmin. Identical score arithmetic + tie-break
// order as the passing round; restructured for conflict-free LDS and 2x
// register blocking (8 rows x 8 ks per thread).
__global__ __launch_bounds__(256, 2) void vq_np(
    const float* __restrict__ x,      // [N_TOK, DIM]
    const float* __restrict__ emb,    // [KCB, DIM]
    const float* __restrict__ A,      // [N_TOK] fp32 ||x||^2 (numpy order)
    const float* __restrict__ C,      // [KCB]  fp32 ||e||^2
    float* __restrict__ out,          // [1 + N*D + N]
    double* __restrict__ lossAcc)
{
    __shared__ float xs[MROWS][DIM];  // 65536 B; xf reads are broadcast, no pad needed
    __shared__ float est[DC][ESD];    // 8256 B; d-major, conflict-free float2 reads
    __shared__ float sA[MROWS];
    __shared__ int   sIdx[MROWS];
    __shared__ double sRed[4];

    const int tid = threadIdx.x;
    const int c = tid & 31;           // k-pair group: ks {2c+64j, 2c+1+64j}
    const int r = tid >> 5;           // row group 0..7, owns rows r*8..r*8+7
    const int rowBase = blockIdx.x * MROWS;

    if (tid < MROWS) sA[tid] = A[rowBase + tid];

    // ---- stage x tile once: 64 rows x 256 d, coalesced float4 ----
    #pragma unroll
    for (int p = 0; p < 16; ++p) {
        int flat = p * 256 + tid;
        int row = flat >> 6, d = (flat & 63) * 4;
        float4 v = *(const float4*)(x + (size_t)(rowBase + row) * DIM + d);
        *(float4*)&xs[row][d] = v;
    }

    float m1[8];
    int   i1[8];
    #pragma unroll
    for (int ri = 0; ri < 8; ++ri) { m1[ri] = 3.4e38f; i1[ri] = 0; }

    for (int kt = 0; kt < NKT; ++kt) {
        float acc[8][8];
        #pragma unroll
        for (int ri = 0; ri < 8; ++ri)
            #pragma unroll
            for (int kk = 0; kk < 8; ++kk) acc[ri][kk] = 0.f;

        for (int dc = 0; dc < NDC; ++dc) {
            // thread stages row k = kt*KT+tid, dims dc*8..dc*8+7 (transposed)
            const float* src = emb + (size_t)(kt * KT + tid) * DIM + dc * DC;
            float4 ea = *(const float4*)(src);
            float4 eb = *(const float4*)(src + 4);
            __syncthreads();              // prior-iter readers done (also covers xs staging)
            est[0][tid] = ea.x; est[1][tid] = ea.y; est[2][tid] = ea.z; est[3][tid] = ea.w;
            est[4][tid] = eb.x; est[5][tid] = eb.y; est[6][tid] = eb.z; est[7][tid] = eb.w;
            __syncthreads();
            #pragma unroll
            for (int d4 = 0; d4 < 2; ++d4) {
                float4 xf[8];
                #pragma unroll
                for (int ri = 0; ri < 8; ++ri)
                    xf[ri] = *(const float4*)&xs[r * 8 + ri][dc * DC + d4 * 4];
                #pragma unroll
                for (int dd = 0; dd < 4; ++dd) {
                    float2 ev[4];
                    #pragma unroll
                    for (int j = 0; j < 4; ++j)
                        ev[j] = *(const float2*)&est[d4 * 4 + dd][2 * c + 64 * j];
                    #pragma unroll
                    for (int ri = 0; ri < 8; ++ri) {
                        float xv = (dd == 0) ? xf[ri].x : (dd == 1) ? xf[ri].y
                                 : (dd == 2) ? xf[ri].z : xf[ri].w;
                        #pragma unroll
                        for (int j = 0; j < 4; ++j) {
                            acc[ri][2 * j]     = fmaf(xv, ev[j].x, acc[ri][2 * j]);
                            acc[ri][2 * j + 1] = fmaf(xv, ev[j].y, acc[ri][2 * j + 1]);
                        }
                    }
                }
            }
        }
        // scores: s = fl32(fl32(A - 2*dot) + C); per-thread k-visit order ascending
        #pragma unroll
        for (int j = 0; j < 4; ++j) {
            float2 Cv = *(const float2*)&C[kt * KT + 2 * c + 64 * j];
            #pragma unroll
            for (int p = 0; p < 2; ++p) {
                int kg = kt * KT + 2 * c + 64 * j + p;
                float Ck = (p == 0) ? Cv.x : Cv.y;
                #pragma unroll
                for (int ri = 0; ri < 8; ++ri) {
                    float tmp = sA[r * 8 + ri] - 2.0f * acc[ri][2 * j + p];
                    float s   = tmp + Ck;
                    if (s < m1[ri]) { m1[ri] = s; i1[ri] = kg; }
                }
            }
        }
    }

    // ---- cross-lane argmin merge over the 32 lanes of each r-group ----
    #pragma unroll
    for (int ri = 0; ri < 8; ++ri) {
        float a = m1[ri]; int ja = i1[ri];
        #pragma unroll
        for (int off = 1; off <= 16; off <<= 1) {
            float b  = __shfl_xor(a, off, 64);
            int   jb = __shfl_xor(ja, off, 64);
            if (b < a || (b == a && jb < ja)) { a = b; ja = jb; }
        }
        if (c == 0) sIdx[r * 8 + ri] = ja;
    }
    __syncthreads();

    // ---- outputs: index (as float), quantized (exact gather), loss partial ----
    if (tid < MROWS) {
        out[1 + (size_t)N_TOK * DIM + rowBase + tid] = (float)sIdx[tid];
    }
    double lsum = 0.0;
    for (int row = 0; row < MROWS; ++row) {
        int idx = sIdx[row];
        float q  = emb[(size_t)idx * DIM + tid];
        float xv = xs[row][tid];
        out[1 + (size_t)(rowBase + row) * DIM + tid] = q;
        double df = (double)q - (double)xv;
        lsum += df * df;
    }
    #pragma unroll
    for (int off = 1; off < 64; off <<= 1) lsum += __shfl_xor(lsum, off, 64);
    __syncthreads();
    if ((tid & 63) == 0) sRed[tid >> 6] = lsum;
    __syncthreads();
    if (tid == 0) {
        atomicAdd(lossAcc, sRed[0] + sRed[1] + sRed[2] + sRed[3]);
    }
}

// ---------------------------------------------------------------------------
__global__ void finalize_kernel(const double* __restrict__ lossAcc, float* __restrict__ out) {
    out[0] = (float)(0.5 * (*lossAcc) / (double)((size_t)N_TOK * DIM));
}

extern "C" void kernel_launch(void* const* d_in, const int* in_sizes, int n_in,
                              void* d_out, int out_size, void* d_ws, size_t ws_size,
                              hipStream_t stream) {
    const float* x   = (const float*)d_in[0];   // [16,2048,256] fp32
    const float* emb = (const float*)d_in[1];   // [4096,256] fp32
    float* out = (float*)d_out;

    double* lossAcc = (double*)d_ws;
    float*  A       = (float*)((char*)d_ws + WS_A);
    float*  C       = (float*)((char*)d_ws + WS_C);

    hipMemsetAsync(d_ws, 0, 16, stream);
    xsq_np_kernel<<<N_TOK / 4, 256, 0, stream>>>(x, A);
    esq_np_kernel<<<KCB / 4, 256, 0, stream>>>(emb, C);
    vq_np<<<N_TOK / MROWS, 256, 0, stream>>>(x, emb, A, C, out, lossAcc);
    finalize_kernel<<<1, 1, 0, stream>>>(lossAcc, out);
}